// Round 11
// baseline (281.036 us; speedup 1.0000x reference)
//
#include <hip/hip_runtime.h>

#define N_NODESC 100000
#define N_EDGESC 1600000
#define NB_BUCKETS 391      // ceil(100000/256)
#define BUCKET_CAP 5120     // mean 4092, sigma 64 -> +16 sigma headroom (fixed graph)
#define CHUNK_A 4096
// IN_C = 128, HID_C = 128, OUT_C = 64

typedef __attribute__((ext_vector_type(4))) float floatx4;
typedef __attribute__((ext_vector_type(8))) short shortx8;

// ---------------- bf16 helpers ----------------
__device__ __forceinline__ unsigned short f32_to_bf16_rne(float f) {
    unsigned int u = __float_as_uint(f);
    unsigned int r = u + 0x7fffu + ((u >> 16) & 1u);
    return (unsigned short)(r >> 16);
}
__device__ __forceinline__ float bf16_to_f32(unsigned short h) {
    return __uint_as_float(((unsigned int)h) << 16);
}
__device__ __forceinline__ float bflo(unsigned int u) { return __uint_as_float(u << 16); }
__device__ __forceinline__ float bfhi(unsigned int u) { return __uint_as_float(u & 0xffff0000u); }
__device__ __forceinline__ unsigned int pack2bf(float a, float b) {
    return ((unsigned int)f32_to_bf16_rne(b) << 16) | (unsigned int)f32_to_bf16_rne(a);
}

// ---------------- fused W pre-pack (W1 + W2) + fixed-stride gcur init ----------
__global__ __launch_bounds__(256) void k_wfrag_all(const float* __restrict__ W1,
        const float* __restrict__ W2,
        unsigned short* __restrict__ w1hi, unsigned short* __restrict__ w1lo,
        unsigned short* __restrict__ w2hi, unsigned short* __restrict__ w2lo,
        int* __restrict__ gcur) {
    int t = threadIdx.x;
    if (blockIdx.x == 0)
        for (int i = t; i < NB_BUCKETS; i += 256) gcur[i] = i * BUCKET_CAP;
    int idx = blockIdx.x * 256 + t;
    float f;
    int k, col, C, o;
    unsigned short *phi, *plo;
    if (idx < 16384) {
        k = idx >> 7; col = idx & 127; C = 8;
        f = W1[idx]; phi = w1hi; plo = w1lo;
    } else {
        int idx2 = idx - 16384;
        k = idx2 >> 6; col = idx2 & 63; C = 4;
        f = W2[idx2]; phi = w2hi; plo = w2lo;
    }
    unsigned short hi = f32_to_bf16_rne(f);
    unsigned short lo = f32_to_bf16_rne(f - bf16_to_f32(hi));
    int kc = k >> 5, q = (k >> 3) & 3, j = k & 7;
    int c = col >> 4, n = col & 15;
    o = (((kc * C + c) * 4 + q) * 16 + n) * 8 + j;
    phi[o] = hi; plo[o] = lo;
}

// ---------------- phase A: bucket edges by dst>>8 into fixed-stride tmp windows.
// 1024-thread blocks, register-cached edges (r10-proven). -----------------------
__global__ __launch_bounds__(1024) void k_bucket(const int* __restrict__ src,
        const int* __restrict__ dst, int* __restrict__ gcur,
        unsigned int* __restrict__ tmp) {
    __shared__ int hist[NB_BUCKETS];
    int t = threadIdx.x;
    for (int i = t; i < NB_BUCKETS; i += 1024) hist[i] = 0;
    __syncthreads();
    int base = blockIdx.x * CHUNK_A;
    int end = min(base + CHUNK_A, N_EDGESC);
    unsigned int cv[4];
    int cb[4];
#pragma unroll
    for (int k = 0; k < 4; ++k) {
        int e = base + t + k * 1024;
        cb[k] = -1;
        if (e < end) {
            int s = src[e], d = dst[e];
            cv[k] = ((unsigned int)s << 8) | (unsigned int)(d & 255);
            cb[k] = d >> 8;
            atomicAdd(&hist[cb[k]], 1);
        }
    }
    __syncthreads();
    for (int i = t; i < NB_BUCKETS; i += 1024) {
        int c = hist[i];
        hist[i] = (c > 0) ? atomicAdd(&gcur[i], c) : 0;
    }
    __syncthreads();
#pragma unroll
    for (int k = 0; k < 4; ++k) {
        if (cb[k] >= 0) {
            int pos = atomicAdd(&hist[cb[k]], 1);
            tmp[pos] = cv[k];
        }
    }
}

// ---------------- phase B: TWO half-blocks per bucket (782 blocks, 2x the r3
// parallelism). Each block filters its 128-node half (bit 7 of the node byte),
// scans 128 bins, and fills independently: half 0 forward from window start,
// half 1 anchored at window end (rp = end - total1 + scan). Gap in the middle
// of each window is harmless (row_ptr/deg-driven consumers). -------------------
__global__ __launch_bounds__(1024) void k_place(const unsigned int* __restrict__ tmp,
        const int* __restrict__ gcur,
        int* __restrict__ swsrc, int* __restrict__ deg,
        int* __restrict__ row_ptr, float* __restrict__ dinv) {
    __shared__ unsigned int eb[BUCKET_CAP];
    __shared__ int hist[128], scan[128], lcur[128];
    int b2 = blockIdx.x, t = threadIdx.x;
    int b = b2 >> 1, h = b2 & 1;
    int start = b * BUCKET_CAP;
    int end = gcur[b];   // after phase A, gcur[b] == start + count(b)
    int cnt = end - start;
    if (t < 128) hist[t] = 0;
    for (int i = t; i < cnt; i += 1024) eb[i] = tmp[start + i];
    __syncthreads();
    for (int i = t; i < cnt; i += 1024) {
        unsigned int v = eb[i];
        if ((int)((v >> 7) & 1u) == h) atomicAdd(&hist[v & 127u], 1);
    }
    __syncthreads();
    int own = (t < 128) ? hist[t] : 0;
    if (t < 128) scan[t] = own;
    __syncthreads();
    for (int off = 1; off < 128; off <<= 1) {
        int add = (t >= off && t < 128) ? scan[t - off] : 0;
        __syncthreads();
        if (t < 128) scan[t] += add;
        __syncthreads();
    }
    int total = scan[127];   // inclusive total of this half
    if (t < 128) {
        int excl = scan[t] - own;
        int rp = h ? (end - total + excl) : (start + excl);
        lcur[t] = rp;
        int node = (b << 8) + (h << 7) + t;
        if (node < N_NODESC) {
            deg[node] = own;
            row_ptr[node] = rp;
            dinv[node] = rsqrtf((float)own + 1.0f);
        }
    }
    __syncthreads();
    for (int i = t; i < cnt; i += 1024) {
        unsigned int v = eb[i];
        if ((int)((v >> 7) & 1u) == h) {
            int pos = atomicAdd(&lcur[v & 127u], 1);
            swsrc[pos] = (int)(v >> 8);
        }
    }
}

// ---------------- GEMM via MFMA: H[N,NOUT](bf16) = (A[N,128] @ W) * dinv[row].
// Epilogue LDS tile is WAVE-PRIVATE (etile[wv]) -> no __syncthreads; only
// intra-wave LDS ordering (wave_barrier + lgkmcnt drain) is required. ----------
template<int NOUT, int AFP32>
__global__ __launch_bounds__(256) void k_gemm_mfma(const void* __restrict__ Xv,
        const unsigned short* __restrict__ whi, const unsigned short* __restrict__ wlo,
        const float* __restrict__ dinv, unsigned short* __restrict__ H) {
    constexpr int C = NOUT / 16;
    constexpr int PITCH = NOUT + 4;
    __shared__ __align__(16) float etile[4][16][PITCH];
    int wv = threadIdx.x >> 6, lane = threadIdx.x & 63;
    int n16 = lane & 15, q = lane >> 4;
    int rowBase = blockIdx.x * 128 + wv * 32;
    floatx4 acc[2][C];
#pragma unroll
    for (int m = 0; m < 2; ++m)
#pragma unroll
        for (int c = 0; c < C; ++c) acc[m][c] = (floatx4){0.f, 0.f, 0.f, 0.f};

    const shortx8* whi8 = (const shortx8*)whi;
    const shortx8* wlo8 = (const shortx8*)wlo;

    for (int kc = 0; kc < 4; ++kc) {
        shortx8 ahi[2], alo[2];
#pragma unroll
        for (int m = 0; m < 2; ++m) {
            int r = rowBase + m * 16 + n16;
            if (r >= N_NODESC) r = N_NODESC - 1;
            if (AFP32) {
                const float* xp = &((const float*)Xv)[(size_t)r * 128 + kc * 32 + q * 8];
                floatx4 x0 = *(const floatx4*)xp;
                floatx4 x1 = *(const floatx4*)(xp + 4);
#pragma unroll
                for (int jj = 0; jj < 4; ++jj) {
                    unsigned short h0 = f32_to_bf16_rne(x0[jj]);
                    ahi[m][jj] = (short)h0;
                    alo[m][jj] = (short)f32_to_bf16_rne(x0[jj] - bf16_to_f32(h0));
                    unsigned short h1 = f32_to_bf16_rne(x1[jj]);
                    ahi[m][jj + 4] = (short)h1;
                    alo[m][jj + 4] = (short)f32_to_bf16_rne(x1[jj] - bf16_to_f32(h1));
                }
            } else {
                const unsigned short* xp = &((const unsigned short*)Xv)[(size_t)r * 128 + kc * 32 + q * 8];
                ahi[m] = *(const shortx8*)xp;
            }
        }
#pragma unroll
        for (int c = 0; c < C; ++c) {
            int fo = (kc * C + c) * 64 + lane;
            shortx8 bhi = whi8[fo];
            shortx8 blo = wlo8[fo];
#pragma unroll
            for (int m = 0; m < 2; ++m) {
                acc[m][c] = __builtin_amdgcn_mfma_f32_16x16x32_bf16(ahi[m], bhi, acc[m][c], 0, 0, 0);
                if (AFP32)
                    acc[m][c] = __builtin_amdgcn_mfma_f32_16x16x32_bf16(alo[m], bhi, acc[m][c], 0, 0, 0);
                acc[m][c] = __builtin_amdgcn_mfma_f32_16x16x32_bf16(ahi[m], blo, acc[m][c], 0, 0, 0);
            }
        }
    }
    constexpr int CPL = NOUT / 4;
#pragma unroll
    for (int m = 0; m < 2; ++m) {
        __builtin_amdgcn_wave_barrier();
#pragma unroll
        for (int c = 0; c < C; ++c)
#pragma unroll
            for (int reg = 0; reg < 4; ++reg)
                etile[wv][q * 4 + reg][c * 16 + n16] = acc[m][c][reg];
        asm volatile("s_waitcnt lgkmcnt(0)" ::: "memory");
        __builtin_amdgcn_wave_barrier();
        int row = lane >> 2, cb = lane & 3;
        int r = rowBase + m * 16 + row;
        if (r < N_NODESC) {
            float dv = dinv[r];
            unsigned int po[CPL / 2];
#pragma unroll
            for (int i = 0; i < CPL / 4; ++i) {
                floatx4 v = *(const floatx4*)&etile[wv][row][cb * CPL + i * 4];
                po[i * 2 + 0] = pack2bf(v[0] * dv, v[1] * dv);
                po[i * 2 + 1] = pack2bf(v[2] * dv, v[3] * dv);
            }
            unsigned int* op = (unsigned int*)&H[(size_t)r * NOUT + cb * CPL];
#pragma unroll
            for (int i = 0; i < CPL / 8; ++i)
                *(uint4*)(op + i * 4) = *(uint4*)&po[i * 4];
        }
        asm volatile("s_waitcnt lgkmcnt(0)" ::: "memory");
        __builtin_amdgcn_wave_barrier();
    }
}

// ---------------- FUSED: aggregation d=128 (layer-1 agg, +b1, relu) + layer-2
// GEMM -> H2 bf16. 512 threads / 32 nodes per block; waves pull nodes from an
// LDS counter (DYNAMIC assignment) so the pre-MFMA __syncthreads waits on the
// balanced max, not a fixed 4-node slice (r3's 13% straggler tax). Per-node
// arithmetic identical to r3 -> bitwise-same H2. --------------------------------
__global__ __launch_bounds__(512) void k_agg_gemm(const unsigned short* __restrict__ Hb,
        const int* __restrict__ swsrc, const int* __restrict__ row_ptr,
        const int* __restrict__ deg, const float* __restrict__ dinv,
        const float* __restrict__ bias,
        const unsigned short* __restrict__ w2hi, const unsigned short* __restrict__ w2lo,
        unsigned short* __restrict__ H2) {
    __shared__ __align__(16) unsigned int lds_h[32][64];   // 32 nodes x 128 bf16
    __shared__ int nxt;
    int wv = threadIdx.x >> 6, lane = threadIdx.x & 63;
    int g = lane >> 4, l16 = lane & 15;
    int nb = blockIdx.x * 32;
    if (threadIdx.x == 0) nxt = 0;
    __syncthreads();

    for (;;) {
        int n;
        if (lane == 0) n = atomicAdd(&nxt, 1);
        n = __shfl(n, 0);
        if (n >= 32) break;
        int node = nb + n;
        int start = row_ptr[node];
        int end = start + deg[node];
        float acc[8] = {0.f, 0.f, 0.f, 0.f, 0.f, 0.f, 0.f, 0.f};
        int j = start + g;
        for (; j + 4 < end; j += 8) {
            int s0 = swsrc[j];
            int s1 = swsrc[j + 4];
            uint4 v0 = *(const uint4*)(Hb + (size_t)s0 * 128 + l16 * 8);
            uint4 v1 = *(const uint4*)(Hb + (size_t)s1 * 128 + l16 * 8);
            acc[0] += bflo(v0.x) + bflo(v1.x);
            acc[1] += bfhi(v0.x) + bfhi(v1.x);
            acc[2] += bflo(v0.y) + bflo(v1.y);
            acc[3] += bfhi(v0.y) + bfhi(v1.y);
            acc[4] += bflo(v0.z) + bflo(v1.z);
            acc[5] += bfhi(v0.z) + bfhi(v1.z);
            acc[6] += bflo(v0.w) + bflo(v1.w);
            acc[7] += bfhi(v0.w) + bfhi(v1.w);
        }
        if (j < end) {
            int s0 = swsrc[j];
            uint4 v0 = *(const uint4*)(Hb + (size_t)s0 * 128 + l16 * 8);
            acc[0] += bflo(v0.x); acc[1] += bfhi(v0.x);
            acc[2] += bflo(v0.y); acc[3] += bfhi(v0.y);
            acc[4] += bflo(v0.z); acc[5] += bfhi(v0.z);
            acc[6] += bflo(v0.w); acc[7] += bfhi(v0.w);
        }
#pragma unroll
        for (int k = 0; k < 8; ++k) {
            acc[k] += __shfl_xor(acc[k], 16);
            acc[k] += __shfl_xor(acc[k], 32);
        }
        if (g == 0) {
            float dv = dinv[node];
            uint4 sv = *(const uint4*)(Hb + (size_t)node * 128 + l16 * 8);
            floatx4 b0 = *(const floatx4*)&bias[l16 * 8];
            floatx4 b1 = *(const floatx4*)&bias[l16 * 8 + 4];
            float o0 = dv * (acc[0] + bflo(sv.x)) + b0[0];
            float o1 = dv * (acc[1] + bfhi(sv.x)) + b0[1];
            float o2 = dv * (acc[2] + bflo(sv.y)) + b0[2];
            float o3 = dv * (acc[3] + bfhi(sv.y)) + b0[3];
            float o4 = dv * (acc[4] + bflo(sv.z)) + b1[0];
            float o5 = dv * (acc[5] + bfhi(sv.z)) + b1[1];
            float o6 = dv * (acc[6] + bflo(sv.w)) + b1[2];
            float o7 = dv * (acc[7] + bfhi(sv.w)) + b1[3];
            uint4 o;
            o.x = pack2bf(fmaxf(o0, 0.f), fmaxf(o1, 0.f));
            o.y = pack2bf(fmaxf(o2, 0.f), fmaxf(o3, 0.f));
            o.z = pack2bf(fmaxf(o4, 0.f), fmaxf(o5, 0.f));
            o.w = pack2bf(fmaxf(o6, 0.f), fmaxf(o7, 0.f));
            // swizzled LDS store: word col (l16*4) ^ ((n&7)*4)  (16B aligned)
            int pcol = (l16 * 4) ^ ((n & 7) * 4);
            *(uint4*)&lds_h[n][pcol] = o;
        }
    }
    __syncthreads();

    // ---- layer-2 GEMM: 8 waves, wave wv -> rows (wv>>2)*16..+16, cols (wv&3)*16..+16
    int q = lane >> 4, n16 = lane & 15;
    int rowgrp = wv >> 2, colgrp = wv & 3;
    floatx4 accm = (floatx4){0.f, 0.f, 0.f, 0.f};
    const shortx8* whi8 = (const shortx8*)w2hi;
    const shortx8* wlo8 = (const shortx8*)w2lo;
#pragma unroll
    for (int kc = 0; kc < 4; ++kc) {
        int pcol = (kc * 16 + q * 4) ^ ((n16 & 7) * 4);
        shortx8 ahi = *(const shortx8*)&lds_h[rowgrp * 16 + n16][pcol];
        int fo = (kc * 4 + colgrp) * 64 + lane;
        shortx8 bhi = whi8[fo];
        shortx8 blo = wlo8[fo];
        accm = __builtin_amdgcn_mfma_f32_16x16x32_bf16(ahi, bhi, accm, 0, 0, 0);
        accm = __builtin_amdgcn_mfma_f32_16x16x32_bf16(ahi, blo, accm, 0, 0, 0);
    }
    // C layout: rel col = lane&15, rel row = (lane>>4)*4 + reg
    int crow = q * 4;
    int ccol = colgrp * 16 + n16;
#pragma unroll
    for (int reg = 0; reg < 4; ++reg) {
        int r = nb + rowgrp * 16 + crow + reg;
        float dv = dinv[r];
        H2[(size_t)r * 64 + ccol] = f32_to_bf16_rne(accm[reg] * dv);
    }
}

// ---------------- aggregation d=64 (bf16 in, fp32 out): wave/node, 8 groups of 8
// lanes (16B each), unroll 2 -> 16 gathers in flight. R9-exact. ----------------
__global__ __launch_bounds__(256) void k_agg64(const unsigned short* __restrict__ Hb,
        const int* __restrict__ swsrc, const int* __restrict__ row_ptr,
        const int* __restrict__ deg, const float* __restrict__ dinv,
        const float* __restrict__ bias, float* __restrict__ out) {
    int node = blockIdx.x * 4 + (threadIdx.x >> 6);
    int lane = threadIdx.x & 63;
    int g = lane >> 3, l8 = lane & 7;
    int start = row_ptr[node];
    int end = start + deg[node];
    float acc[8] = {0.f, 0.f, 0.f, 0.f, 0.f, 0.f, 0.f, 0.f};
    int j = start + g;
    for (; j + 8 < end; j += 16) {
        int s0 = swsrc[j];
        int s1 = swsrc[j + 8];
        uint4 v0 = *(const uint4*)(Hb + (size_t)s0 * 64 + l8 * 8);
        uint4 v1 = *(const uint4*)(Hb + (size_t)s1 * 64 + l8 * 8);
        acc[0] += bflo(v0.x) + bflo(v1.x);
        acc[1] += bfhi(v0.x) + bfhi(v1.x);
        acc[2] += bflo(v0.y) + bflo(v1.y);
        acc[3] += bfhi(v0.y) + bfhi(v1.y);
        acc[4] += bflo(v0.z) + bflo(v1.z);
        acc[5] += bfhi(v0.z) + bfhi(v1.z);
        acc[6] += bflo(v0.w) + bflo(v1.w);
        acc[7] += bfhi(v0.w) + bfhi(v1.w);
    }
    if (j < end) {
        int s0 = swsrc[j];
        uint4 v0 = *(const uint4*)(Hb + (size_t)s0 * 64 + l8 * 8);
        acc[0] += bflo(v0.x); acc[1] += bfhi(v0.x);
        acc[2] += bflo(v0.y); acc[3] += bfhi(v0.y);
        acc[4] += bflo(v0.z); acc[5] += bfhi(v0.z);
        acc[6] += bflo(v0.w); acc[7] += bfhi(v0.w);
    }
#pragma unroll
    for (int i = 0; i < 8; ++i) {
        acc[i] += __shfl_xor(acc[i], 8);
        acc[i] += __shfl_xor(acc[i], 16);
        acc[i] += __shfl_xor(acc[i], 32);
    }
    if (g == 0) {
        float dv = dinv[node];
        uint4 sv = *(const uint4*)(Hb + (size_t)node * 64 + l8 * 8);
        floatx4 b0 = *(const floatx4*)&bias[l8 * 8];
        floatx4 b1 = *(const floatx4*)&bias[l8 * 8 + 4];
        floatx4 o0, o1;
        o0[0] = dv * (acc[0] + bflo(sv.x)) + b0[0];
        o0[1] = dv * (acc[1] + bfhi(sv.x)) + b0[1];
        o0[2] = dv * (acc[2] + bflo(sv.y)) + b0[2];
        o0[3] = dv * (acc[3] + bfhi(sv.y)) + b0[3];
        o1[0] = dv * (acc[4] + bflo(sv.z)) + b1[0];
        o1[1] = dv * (acc[5] + bfhi(sv.z)) + b1[1];
        o1[2] = dv * (acc[6] + bflo(sv.w)) + b1[2];
        o1[3] = dv * (acc[7] + bfhi(sv.w)) + b1[3];
        *(floatx4*)&out[(size_t)node * 64 + l8 * 8] = o0;
        *(floatx4*)&out[(size_t)node * 64 + l8 * 8 + 4] = o1;
    }
}

extern "C" void kernel_launch(void* const* d_in, const int* in_sizes, int n_in,
                              void* d_out, int out_size, void* d_ws, size_t ws_size,
                              hipStream_t stream) {
    const float* x  = (const float*)d_in[0];
    const int*   ei = (const int*)d_in[1];
    const float* W1 = (const float*)d_in[2];
    const float* b1 = (const float*)d_in[3];
    const float* W2 = (const float*)d_in[4];
    const float* b2 = (const float*)d_in[5];
    float* out = (float*)d_out;
    const int* src = ei;
    const int* dst = ei + N_EDGESC;

    char* ws = (char*)d_ws;
    size_t off = 0;
    auto alloc = [&](size_t bytes) -> void* {
        off = (off + 255) & ~(size_t)255;
        void* p = ws + off;
        off += bytes;
        return p;
    };
    const size_t CSR_SLOTS = (size_t)NB_BUCKETS * BUCKET_CAP;   // 2,001,920
    int*   deg     = (int*)  alloc((size_t)N_NODESC * 4);
    float* dinv    = (float*)alloc((size_t)N_NODESC * 4);
    int*   row_ptr = (int*)  alloc((size_t)N_NODESC * 4);
    int*   gcur    = (int*)  alloc(NB_BUCKETS * 4);
    unsigned int* tmp   = (unsigned int*)alloc(CSR_SLOTS * 4);
    int*   swsrc   = (int*)  alloc(CSR_SLOTS * 4);
    unsigned short* w1hi = (unsigned short*)alloc(128 * 128 * 2);
    unsigned short* w1lo = (unsigned short*)alloc(128 * 128 * 2);
    unsigned short* w2hi = (unsigned short*)alloc(128 * 64 * 2);
    unsigned short* w2lo = (unsigned short*)alloc(128 * 64 * 2);
    unsigned short* h1b  = (unsigned short*)alloc((size_t)N_NODESC * 128 * 2);
    unsigned short* h2b  = (unsigned short*)alloc((size_t)N_NODESC * 128 * 2);
    // NOTE: h2b must NOT alias h1b — k_agg_gemm gathers from h1b while writing h2b.

    const int nbGemm = (N_NODESC + 127) / 128;              // 782
    const int nbBkt  = (N_EDGESC + CHUNK_A - 1) / CHUNK_A;  // 391

    k_wfrag_all<<<(16384 + 8192) / 256, 256, 0, stream>>>(W1, W2, w1hi, w1lo, w2hi, w2lo, gcur);
    k_bucket<<<nbBkt, 1024, 0, stream>>>(src, dst, gcur, tmp);
    k_place<<<NB_BUCKETS * 2, 1024, 0, stream>>>(tmp, gcur, swsrc, deg, row_ptr, dinv);

    k_gemm_mfma<128, 1><<<nbGemm, 256, 0, stream>>>(x, w1hi, w1lo, dinv, h1b);
    k_agg_gemm<<<N_NODESC / 32, 512, 0, stream>>>(h1b, swsrc, row_ptr, deg, dinv, b1,
                                                  w2hi, w2lo, h2b);
    k_agg64<<<N_NODESC / 4, 256, 0, stream>>>(h2b, swsrc, row_ptr, deg, dinv, b2, out);
}

// Round 12
// 276.087 us; speedup vs baseline: 1.0179x; 1.0179x over previous
//
#include <hip/hip_runtime.h>

#define N_NODESC 100000
#define N_EDGESC 1600000
#define NB_BUCKETS 391      // ceil(100000/256)
#define BUCKET_CAP 5120     // mean 4092, sigma 64 -> +16 sigma headroom (fixed graph)
#define CHUNK_A 4096
// IN_C = 128, HID_C = 128, OUT_C = 64

typedef __attribute__((ext_vector_type(4))) float floatx4;
typedef __attribute__((ext_vector_type(8))) short shortx8;

// ---------------- bf16 helpers ----------------
__device__ __forceinline__ unsigned short f32_to_bf16_rne(float f) {
    unsigned int u = __float_as_uint(f);
    unsigned int r = u + 0x7fffu + ((u >> 16) & 1u);
    return (unsigned short)(r >> 16);
}
__device__ __forceinline__ float bf16_to_f32(unsigned short h) {
    return __uint_as_float(((unsigned int)h) << 16);
}
__device__ __forceinline__ float bflo(unsigned int u) { return __uint_as_float(u << 16); }
__device__ __forceinline__ float bfhi(unsigned int u) { return __uint_as_float(u & 0xffff0000u); }
__device__ __forceinline__ unsigned int pack2bf(float a, float b) {
    return ((unsigned int)f32_to_bf16_rne(b) << 16) | (unsigned int)f32_to_bf16_rne(a);
}

// ---------------- fused W pre-pack (W1 + W2) + fixed-stride gcur init ----------
__global__ __launch_bounds__(256) void k_wfrag_all(const float* __restrict__ W1,
        const float* __restrict__ W2,
        unsigned short* __restrict__ w1hi, unsigned short* __restrict__ w1lo,
        unsigned short* __restrict__ w2hi, unsigned short* __restrict__ w2lo,
        int* __restrict__ gcur) {
    int t = threadIdx.x;
    if (blockIdx.x == 0)
        for (int i = t; i < NB_BUCKETS; i += 256) gcur[i] = i * BUCKET_CAP;
    int idx = blockIdx.x * 256 + t;
    float f;
    int k, col, C, o;
    unsigned short *phi, *plo;
    if (idx < 16384) {
        k = idx >> 7; col = idx & 127; C = 8;
        f = W1[idx]; phi = w1hi; plo = w1lo;
    } else {
        int idx2 = idx - 16384;
        k = idx2 >> 6; col = idx2 & 63; C = 4;
        f = W2[idx2]; phi = w2hi; plo = w2lo;
    }
    unsigned short hi = f32_to_bf16_rne(f);
    unsigned short lo = f32_to_bf16_rne(f - bf16_to_f32(hi));
    int kc = k >> 5, q = (k >> 3) & 3, j = k & 7;
    int c = col >> 4, n = col & 15;
    o = (((kc * C + c) * 4 + q) * 16 + n) * 8 + j;
    phi[o] = hi; plo[o] = lo;
}

// ---------------- phase A: bucket edges by dst>>8 into fixed-stride tmp windows.
// 1024-thread blocks, register-cached edges (r10-proven). -----------------------
__global__ __launch_bounds__(1024) void k_bucket(const int* __restrict__ src,
        const int* __restrict__ dst, int* __restrict__ gcur,
        unsigned int* __restrict__ tmp) {
    __shared__ int hist[NB_BUCKETS];
    int t = threadIdx.x;
    for (int i = t; i < NB_BUCKETS; i += 1024) hist[i] = 0;
    __syncthreads();
    int base = blockIdx.x * CHUNK_A;
    int end = min(base + CHUNK_A, N_EDGESC);
    unsigned int cv[4];
    int cb[4];
#pragma unroll
    for (int k = 0; k < 4; ++k) {
        int e = base + t + k * 1024;
        cb[k] = -1;
        if (e < end) {
            int s = src[e], d = dst[e];
            cv[k] = ((unsigned int)s << 8) | (unsigned int)(d & 255);
            cb[k] = d >> 8;
            atomicAdd(&hist[cb[k]], 1);
        }
    }
    __syncthreads();
    for (int i = t; i < NB_BUCKETS; i += 1024) {
        int c = hist[i];
        hist[i] = (c > 0) ? atomicAdd(&gcur[i], c) : 0;
    }
    __syncthreads();
#pragma unroll
    for (int k = 0; k < 4; ++k) {
        if (cb[k] >= 0) {
            int pos = atomicAdd(&hist[cb[k]], 1);
            tmp[pos] = cv[k];
        }
    }
}

// ---------------- phase B: per-bucket deg/row_ptr/dinv + exact CSR placement.
// Single global pass: bucket window staged in 20KB LDS; histogram, scan, and
// scatter all read from LDS (r3-proven). ----------------------------------------
__global__ __launch_bounds__(1024) void k_place(const unsigned int* __restrict__ tmp,
        const int* __restrict__ gcur,
        int* __restrict__ swsrc, int* __restrict__ deg,
        int* __restrict__ row_ptr, float* __restrict__ dinv) {
    __shared__ unsigned int eb[BUCKET_CAP];
    __shared__ int hist[256], scan[256], lcur[256];
    int b = blockIdx.x, t = threadIdx.x;
    int start = b * BUCKET_CAP;
    int cnt = gcur[b] - start;   // after phase A, gcur[b] == start + count(b)
    if (t < 256) hist[t] = 0;
    for (int i = t; i < cnt; i += 1024) eb[i] = tmp[start + i];
    __syncthreads();
    for (int i = t; i < cnt; i += 1024)
        atomicAdd(&hist[eb[i] & 255u], 1);
    __syncthreads();
    int own = (t < 256) ? hist[t] : 0;
    if (t < 256) scan[t] = own;
    __syncthreads();
    for (int off = 1; off < 256; off <<= 1) {
        int add = (t >= off && t < 256) ? scan[t - off] : 0;
        __syncthreads();
        if (t < 256) scan[t] += add;
        __syncthreads();
    }
    if (t < 256) {
        int rp = start + scan[t] - own;
        lcur[t] = rp;
        int node = (b << 8) + t;
        if (node < N_NODESC) {
            deg[node] = own;
            row_ptr[node] = rp;
            dinv[node] = rsqrtf((float)own + 1.0f);
        }
    }
    __syncthreads();
    for (int i = t; i < cnt; i += 1024) {
        unsigned int v = eb[i];
        int pos = atomicAdd(&lcur[v & 255u], 1);
        swsrc[pos] = (int)(v >> 8);
    }
}

// ---------------- GEMM via MFMA: H[N,NOUT](bf16) = (A[N,128] @ W) * dinv[row].
// Epilogue LDS tile is WAVE-PRIVATE (etile[wv]) -> no __syncthreads; only
// intra-wave LDS ordering (wave_barrier + lgkmcnt drain) is required. ----------
template<int NOUT, int AFP32>
__global__ __launch_bounds__(256) void k_gemm_mfma(const void* __restrict__ Xv,
        const unsigned short* __restrict__ whi, const unsigned short* __restrict__ wlo,
        const float* __restrict__ dinv, unsigned short* __restrict__ H) {
    constexpr int C = NOUT / 16;
    constexpr int PITCH = NOUT + 4;
    __shared__ __align__(16) float etile[4][16][PITCH];
    int wv = threadIdx.x >> 6, lane = threadIdx.x & 63;
    int n16 = lane & 15, q = lane >> 4;
    int rowBase = blockIdx.x * 128 + wv * 32;
    floatx4 acc[2][C];
#pragma unroll
    for (int m = 0; m < 2; ++m)
#pragma unroll
        for (int c = 0; c < C; ++c) acc[m][c] = (floatx4){0.f, 0.f, 0.f, 0.f};

    const shortx8* whi8 = (const shortx8*)whi;
    const shortx8* wlo8 = (const shortx8*)wlo;

    for (int kc = 0; kc < 4; ++kc) {
        shortx8 ahi[2], alo[2];
#pragma unroll
        for (int m = 0; m < 2; ++m) {
            int r = rowBase + m * 16 + n16;
            if (r >= N_NODESC) r = N_NODESC - 1;
            if (AFP32) {
                const float* xp = &((const float*)Xv)[(size_t)r * 128 + kc * 32 + q * 8];
                floatx4 x0 = *(const floatx4*)xp;
                floatx4 x1 = *(const floatx4*)(xp + 4);
#pragma unroll
                for (int jj = 0; jj < 4; ++jj) {
                    unsigned short h0 = f32_to_bf16_rne(x0[jj]);
                    ahi[m][jj] = (short)h0;
                    alo[m][jj] = (short)f32_to_bf16_rne(x0[jj] - bf16_to_f32(h0));
                    unsigned short h1 = f32_to_bf16_rne(x1[jj]);
                    ahi[m][jj + 4] = (short)h1;
                    alo[m][jj + 4] = (short)f32_to_bf16_rne(x1[jj] - bf16_to_f32(h1));
                }
            } else {
                const unsigned short* xp = &((const unsigned short*)Xv)[(size_t)r * 128 + kc * 32 + q * 8];
                ahi[m] = *(const shortx8*)xp;
            }
        }
#pragma unroll
        for (int c = 0; c < C; ++c) {
            int fo = (kc * C + c) * 64 + lane;
            shortx8 bhi = whi8[fo];
            shortx8 blo = wlo8[fo];
#pragma unroll
            for (int m = 0; m < 2; ++m) {
                acc[m][c] = __builtin_amdgcn_mfma_f32_16x16x32_bf16(ahi[m], bhi, acc[m][c], 0, 0, 0);
                if (AFP32)
                    acc[m][c] = __builtin_amdgcn_mfma_f32_16x16x32_bf16(alo[m], bhi, acc[m][c], 0, 0, 0);
                acc[m][c] = __builtin_amdgcn_mfma_f32_16x16x32_bf16(ahi[m], blo, acc[m][c], 0, 0, 0);
            }
        }
    }
    constexpr int CPL = NOUT / 4;
#pragma unroll
    for (int m = 0; m < 2; ++m) {
        __builtin_amdgcn_wave_barrier();
#pragma unroll
        for (int c = 0; c < C; ++c)
#pragma unroll
            for (int reg = 0; reg < 4; ++reg)
                etile[wv][q * 4 + reg][c * 16 + n16] = acc[m][c][reg];
        asm volatile("s_waitcnt lgkmcnt(0)" ::: "memory");
        __builtin_amdgcn_wave_barrier();
        int row = lane >> 2, cb = lane & 3;
        int r = rowBase + m * 16 + row;
        if (r < N_NODESC) {
            float dv = dinv[r];
            unsigned int po[CPL / 2];
#pragma unroll
            for (int i = 0; i < CPL / 4; ++i) {
                floatx4 v = *(const floatx4*)&etile[wv][row][cb * CPL + i * 4];
                po[i * 2 + 0] = pack2bf(v[0] * dv, v[1] * dv);
                po[i * 2 + 1] = pack2bf(v[2] * dv, v[3] * dv);
            }
            unsigned int* op = (unsigned int*)&H[(size_t)r * NOUT + cb * CPL];
#pragma unroll
            for (int i = 0; i < CPL / 8; ++i)
                *(uint4*)(op + i * 4) = *(uint4*)&po[i * 4];
        }
        asm volatile("s_waitcnt lgkmcnt(0)" ::: "memory");
        __builtin_amdgcn_wave_barrier();
    }
}

// ---------------- FUSED: aggregation d=128 (layer-1 agg of prescaled H1, +b1,
// relu) + layer-2 GEMM (128->64, W2 hi/lo, *dinv[row]) -> H2 bf16. r3-proven:
// block = 16 nodes, 4 waves x 4 sequential nodes (gather loop = proven agg128
// shape), bf16 rows staged in 4KB XOR-swizzled LDS, per-wave 16-col MFMA slice. --
__global__ __launch_bounds__(256) void k_agg_gemm(const unsigned short* __restrict__ Hb,
        const int* __restrict__ swsrc, const int* __restrict__ row_ptr,
        const int* __restrict__ deg, const float* __restrict__ dinv,
        const float* __restrict__ bias,
        const unsigned short* __restrict__ w2hi, const unsigned short* __restrict__ w2lo,
        unsigned short* __restrict__ H2) {
    __shared__ __align__(16) unsigned int lds_h[16][64];   // 16 nodes x 128 bf16
    int wv = threadIdx.x >> 6, lane = threadIdx.x & 63;
    int g = lane >> 4, l16 = lane & 15;
    int nb = blockIdx.x * 16;

#pragma unroll
    for (int i = 0; i < 4; ++i) {
        int nt = wv * 4 + i;
        int node = nb + nt;
        int start = row_ptr[node];
        int end = start + deg[node];
        float acc[8] = {0.f, 0.f, 0.f, 0.f, 0.f, 0.f, 0.f, 0.f};
        int j = start + g;
        for (; j + 4 < end; j += 8) {
            int s0 = swsrc[j];
            int s1 = swsrc[j + 4];
            uint4 v0 = *(const uint4*)(Hb + (size_t)s0 * 128 + l16 * 8);
            uint4 v1 = *(const uint4*)(Hb + (size_t)s1 * 128 + l16 * 8);
            acc[0] += bflo(v0.x) + bflo(v1.x);
            acc[1] += bfhi(v0.x) + bfhi(v1.x);
            acc[2] += bflo(v0.y) + bflo(v1.y);
            acc[3] += bfhi(v0.y) + bfhi(v1.y);
            acc[4] += bflo(v0.z) + bflo(v1.z);
            acc[5] += bfhi(v0.z) + bfhi(v1.z);
            acc[6] += bflo(v0.w) + bflo(v1.w);
            acc[7] += bfhi(v0.w) + bfhi(v1.w);
        }
        if (j < end) {
            int s0 = swsrc[j];
            uint4 v0 = *(const uint4*)(Hb + (size_t)s0 * 128 + l16 * 8);
            acc[0] += bflo(v0.x); acc[1] += bfhi(v0.x);
            acc[2] += bflo(v0.y); acc[3] += bfhi(v0.y);
            acc[4] += bflo(v0.z); acc[5] += bfhi(v0.z);
            acc[6] += bflo(v0.w); acc[7] += bfhi(v0.w);
        }
#pragma unroll
        for (int k = 0; k < 8; ++k) {
            acc[k] += __shfl_xor(acc[k], 16);
            acc[k] += __shfl_xor(acc[k], 32);
        }
        if (g == 0) {
            float dv = dinv[node];
            uint4 sv = *(const uint4*)(Hb + (size_t)node * 128 + l16 * 8);
            floatx4 b0 = *(const floatx4*)&bias[l16 * 8];
            floatx4 b1 = *(const floatx4*)&bias[l16 * 8 + 4];
            float o0 = dv * (acc[0] + bflo(sv.x)) + b0[0];
            float o1 = dv * (acc[1] + bfhi(sv.x)) + b0[1];
            float o2 = dv * (acc[2] + bflo(sv.y)) + b0[2];
            float o3 = dv * (acc[3] + bfhi(sv.y)) + b0[3];
            float o4 = dv * (acc[4] + bflo(sv.z)) + b1[0];
            float o5 = dv * (acc[5] + bfhi(sv.z)) + b1[1];
            float o6 = dv * (acc[6] + bflo(sv.w)) + b1[2];
            float o7 = dv * (acc[7] + bfhi(sv.w)) + b1[3];
            uint4 o;
            o.x = pack2bf(fmaxf(o0, 0.f), fmaxf(o1, 0.f));
            o.y = pack2bf(fmaxf(o2, 0.f), fmaxf(o3, 0.f));
            o.z = pack2bf(fmaxf(o4, 0.f), fmaxf(o5, 0.f));
            o.w = pack2bf(fmaxf(o6, 0.f), fmaxf(o7, 0.f));
            // swizzled LDS store: word col (l16*4) ^ ((nt&7)*4)  (16B aligned)
            int pcol = (l16 * 4) ^ ((nt & 7) * 4);
            *(uint4*)&lds_h[nt][pcol] = o;
        }
    }
    __syncthreads();

    // ---- layer-2 GEMM: wave wv computes output cols [wv*16, wv*16+16) ----
    int q = lane >> 4, n16 = lane & 15;
    floatx4 accm = (floatx4){0.f, 0.f, 0.f, 0.f};
    const shortx8* whi8 = (const shortx8*)w2hi;
    const shortx8* wlo8 = (const shortx8*)w2lo;
#pragma unroll
    for (int kc = 0; kc < 4; ++kc) {
        int pcol = (kc * 16 + q * 4) ^ ((n16 & 7) * 4);
        shortx8 ahi = *(const shortx8*)&lds_h[n16][pcol];
        int fo = (kc * 4 + wv) * 64 + lane;
        shortx8 bhi = whi8[fo];
        shortx8 blo = wlo8[fo];
        accm = __builtin_amdgcn_mfma_f32_16x16x32_bf16(ahi, bhi, accm, 0, 0, 0);
        accm = __builtin_amdgcn_mfma_f32_16x16x32_bf16(ahi, blo, accm, 0, 0, 0);
    }
    // C layout: rel col = lane&15, rel row = (lane>>4)*4 + reg
    int crow = (lane >> 4) * 4;
    int ccol = wv * 16 + n16;
#pragma unroll
    for (int reg = 0; reg < 4; ++reg) {
        int r = nb + crow + reg;
        float dv = dinv[r];
        H2[(size_t)r * 64 + ccol] = f32_to_bf16_rne(accm[reg] * dv);
    }
}

// ---------------- aggregation d=64 (bf16 in, fp32 out): wave/node, 8 groups of 8
// lanes (16B each), unroll 2 -> 16 gathers in flight. R9-exact. ----------------
__global__ __launch_bounds__(256) void k_agg64(const unsigned short* __restrict__ Hb,
        const int* __restrict__ swsrc, const int* __restrict__ row_ptr,
        const int* __restrict__ deg, const float* __restrict__ dinv,
        const float* __restrict__ bias, float* __restrict__ out) {
    int node = blockIdx.x * 4 + (threadIdx.x >> 6);
    int lane = threadIdx.x & 63;
    int g = lane >> 3, l8 = lane & 7;
    int start = row_ptr[node];
    int end = start + deg[node];
    float acc[8] = {0.f, 0.f, 0.f, 0.f, 0.f, 0.f, 0.f, 0.f};
    int j = start + g;
    for (; j + 8 < end; j += 16) {
        int s0 = swsrc[j];
        int s1 = swsrc[j + 8];
        uint4 v0 = *(const uint4*)(Hb + (size_t)s0 * 64 + l8 * 8);
        uint4 v1 = *(const uint4*)(Hb + (size_t)s1 * 64 + l8 * 8);
        acc[0] += bflo(v0.x) + bflo(v1.x);
        acc[1] += bfhi(v0.x) + bfhi(v1.x);
        acc[2] += bflo(v0.y) + bflo(v1.y);
        acc[3] += bfhi(v0.y) + bfhi(v1.y);
        acc[4] += bflo(v0.z) + bflo(v1.z);
        acc[5] += bfhi(v0.z) + bfhi(v1.z);
        acc[6] += bflo(v0.w) + bflo(v1.w);
        acc[7] += bfhi(v0.w) + bfhi(v1.w);
    }
    if (j < end) {
        int s0 = swsrc[j];
        uint4 v0 = *(const uint4*)(Hb + (size_t)s0 * 64 + l8 * 8);
        acc[0] += bflo(v0.x); acc[1] += bfhi(v0.x);
        acc[2] += bflo(v0.y); acc[3] += bfhi(v0.y);
        acc[4] += bflo(v0.z); acc[5] += bfhi(v0.z);
        acc[6] += bflo(v0.w); acc[7] += bfhi(v0.w);
    }
#pragma unroll
    for (int i = 0; i < 8; ++i) {
        acc[i] += __shfl_xor(acc[i], 8);
        acc[i] += __shfl_xor(acc[i], 16);
        acc[i] += __shfl_xor(acc[i], 32);
    }
    if (g == 0) {
        float dv = dinv[node];
        uint4 sv = *(const uint4*)(Hb + (size_t)node * 64 + l8 * 8);
        floatx4 b0 = *(const floatx4*)&bias[l8 * 8];
        floatx4 b1 = *(const floatx4*)&bias[l8 * 8 + 4];
        floatx4 o0, o1;
        o0[0] = dv * (acc[0] + bflo(sv.x)) + b0[0];
        o0[1] = dv * (acc[1] + bfhi(sv.x)) + b0[1];
        o0[2] = dv * (acc[2] + bflo(sv.y)) + b0[2];
        o0[3] = dv * (acc[3] + bfhi(sv.y)) + b0[3];
        o1[0] = dv * (acc[4] + bflo(sv.z)) + b1[0];
        o1[1] = dv * (acc[5] + bfhi(sv.z)) + b1[1];
        o1[2] = dv * (acc[6] + bflo(sv.w)) + b1[2];
        o1[3] = dv * (acc[7] + bfhi(sv.w)) + b1[3];
        *(floatx4*)&out[(size_t)node * 64 + l8 * 8] = o0;
        *(floatx4*)&out[(size_t)node * 64 + l8 * 8 + 4] = o1;
    }
}

extern "C" void kernel_launch(void* const* d_in, const int* in_sizes, int n_in,
                              void* d_out, int out_size, void* d_ws, size_t ws_size,
                              hipStream_t stream) {
    const float* x  = (const float*)d_in[0];
    const int*   ei = (const int*)d_in[1];
    const float* W1 = (const float*)d_in[2];
    const float* b1 = (const float*)d_in[3];
    const float* W2 = (const float*)d_in[4];
    const float* b2 = (const float*)d_in[5];
    float* out = (float*)d_out;
    const int* src = ei;
    const int* dst = ei + N_EDGESC;

    char* ws = (char*)d_ws;
    size_t off = 0;
    auto alloc = [&](size_t bytes) -> void* {
        off = (off + 255) & ~(size_t)255;
        void* p = ws + off;
        off += bytes;
        return p;
    };
    const size_t CSR_SLOTS = (size_t)NB_BUCKETS * BUCKET_CAP;   // 2,001,920
    int*   deg     = (int*)  alloc((size_t)N_NODESC * 4);
    float* dinv    = (float*)alloc((size_t)N_NODESC * 4);
    int*   row_ptr = (int*)  alloc((size_t)N_NODESC * 4);
    int*   gcur    = (int*)  alloc(NB_BUCKETS * 4);
    unsigned int* tmp   = (unsigned int*)alloc(CSR_SLOTS * 4);
    int*   swsrc   = (int*)  alloc(CSR_SLOTS * 4);
    unsigned short* w1hi = (unsigned short*)alloc(128 * 128 * 2);
    unsigned short* w1lo = (unsigned short*)alloc(128 * 128 * 2);
    unsigned short* w2hi = (unsigned short*)alloc(128 * 64 * 2);
    unsigned short* w2lo = (unsigned short*)alloc(128 * 64 * 2);
    unsigned short* h1b  = (unsigned short*)alloc((size_t)N_NODESC * 128 * 2);
    unsigned short* h2b  = (unsigned short*)alloc((size_t)N_NODESC * 128 * 2);
    // NOTE: h2b must NOT alias h1b — k_agg_gemm gathers from h1b while writing h2b.

    const int nbGemm = (N_NODESC + 127) / 128;              // 782
    const int nbBkt  = (N_EDGESC + CHUNK_A - 1) / CHUNK_A;  // 391

    k_wfrag_all<<<(16384 + 8192) / 256, 256, 0, stream>>>(W1, W2, w1hi, w1lo, w2hi, w2lo, gcur);
    k_bucket<<<nbBkt, 1024, 0, stream>>>(src, dst, gcur, tmp);
    k_place<<<NB_BUCKETS, 1024, 0, stream>>>(tmp, gcur, swsrc, deg, row_ptr, dinv);

    k_gemm_mfma<128, 1><<<nbGemm, 256, 0, stream>>>(x, w1hi, w1lo, dinv, h1b);
    k_agg_gemm<<<N_NODESC / 16, 256, 0, stream>>>(h1b, swsrc, row_ptr, deg, dinv, b1,
                                                  w2hi, w2lo, h2b);
    k_agg64<<<N_NODESC / 4, 256, 0, stream>>>(h2b, swsrc, row_ptr, deg, dinv, b2, out);
}